// Round 5
// baseline (1744.225 us; speedup 1.0000x reference)
//
#include <hip/hip_runtime.h>
#include <math.h>

// ---------------- problem constants ----------------
#define NN 50000      // nodes
#define MM 12         // neighbors
#define NM 600000     // edges = NN*MM
#define OF 92         // orig node features
#define FF 64         // node feature dim
#define EE 41         // edge feature dim
#define ES 48         // padded edge stride (bf16), cols 41..47 = 0
#define ZZ 169        // 2*FF + EE
#define RPB 96        // rows (edges) per tile = 8 nodes * 12
#define NPB 8         // nodes per tile
#define NTILE 6250    // NN / NPB
#define KSTEPS 6      // 6 * 32 = 192 >= 169
#define MT 6          // M-tiles per tile (96/16)
#define NSLICE 64     // stats accumulator replication
#define PSTRIDE 1024  // floats per slice
#define TPB 512       // threads per block in GEMM passes (8 waves)
#define GRIDP 512     // persistent grid
#define ZR0 24576     // bytes: Z sections 0+1, [96][128 elems] swizzled
#define ZR2 12288     // bytes: Z section 2,   [96][64 elems]  swizzled
#define BUFB (ZR0+ZR2) // 36864 bytes per buffer

typedef __bf16 bf16x8 __attribute__((ext_vector_type(8)));
typedef float  f32x4  __attribute__((ext_vector_type(4)));

__device__ __forceinline__ float lrelu(float x){ return fmaxf(x, 0.01f*x); }
__device__ __forceinline__ float sigm(float x){ return __builtin_amdgcn_rcpf(1.f+__expf(-x)); }
__device__ __forceinline__ float softpl(float x){ return fmaxf(x,0.f) + __logf(1.f+__expf(-fabsf(x))); }
__device__ __forceinline__ unsigned short f2bf(float f){
    __bf16 h = (__bf16)f;
    return __builtin_bit_cast(unsigned short, h);
}
__device__ __forceinline__ float b2f(unsigned short u){
    unsigned int b = ((unsigned int)u) << 16;
    return __builtin_bit_cast(float, b);
}

// async 16B global->LDS
__device__ __forceinline__ void glds16(const void* g, void* l){
    __builtin_amdgcn_global_load_lds(
        (const __attribute__((address_space(1))) void*)g,
        (__attribute__((address_space(3))) void*)l, 16, 0, 0);
}

// ---------------- weight packing into B-fragment layout (bf16) ----------------
__global__ __launch_bounds__(256) void pack_w(const float* __restrict__ Wn,
    const float* __restrict__ We, const float* __restrict__ Wd,
    const float* __restrict__ Wc, unsigned short* __restrict__ dst)
{
    int idx = blockIdx.x*256 + threadIdx.x;
    if (idx >= 4*49152) return;
    int j    = idx & 7;
    int lane = (idx >> 3) & 63;
    int ntks = (idx >> 9) % 96;         // ks*16 + nt
    int L    = idx / 49152;
    int nt = ntks & 15, ks = ntks >> 4;
    int k   = ks*32 + (lane>>4)*8 + j;
    int col = nt*16 + (lane&15);
    float v = 0.f;
    if (k < ZZ) {
        if (L < 3) {
            if (col < 128)                       v = Wn[((size_t)L*ZZ + k)*128 + col];
            else if (col >= 128 && col < 128+EE) v = We[((size_t)L*ZZ + k)*82 + (col-128)];
            else if (col >= 192 && col < 192+EE) v = We[((size_t)L*ZZ + k)*82 + 41 + (col-192)];
        } else {
            if (col < 128) v = Wd[(size_t)k*128 + col];
            else           v = Wc[(size_t)k*128 + (col-128)];
        }
    }
    dst[idx] = f2bf(v);
}

// ---------------- distance ----------------
__global__ __launch_bounds__(256) void k_dist(const float* __restrict__ off,
    const float* __restrict__ apos, const float* __restrict__ cells,
    const int* __restrict__ eidx, float* __restrict__ distb)
{
    int idx = blockIdx.x*256 + threadIdx.x;
    if (idx >= NM) return;
    int n = idx / MM;
    const float* o  = off + (size_t)idx*3;
    const float* cl = cells + (size_t)n*9;
    int n2 = eidx[idx];
    float o0=o[0], o1=o[1], o2=o[2];
    float dd = 1e-12f;
    #pragma unroll
    for (int j=0;j<3;j++){
        float oc = o0*cl[0*3+j] + o1*cl[1*3+j] + o2*cl[2*3+j];
        float d = apos[(size_t)n2*3+j] + oc - apos[(size_t)n*3+j];
        dd += d*d;
    }
    distb[idx] = sqrtf(dd);
}

// ---------------- edge convert: fp32 [NM][41] -> bf16 [NM][48] (pad 0) ----------------
__global__ __launch_bounds__(256) void k_cvt(const float* __restrict__ src,
    unsigned short* __restrict__ e)
{
    int idx = blockIdx.x*256 + threadIdx.x;
    if (idx >= NM*ES) return;
    int gr = idx / ES;
    int c  = idx - gr*ES;
    e[idx] = (c < EE) ? f2bf(src[(size_t)gr*EE + c]) : (unsigned short)0;
}

// ---------------- embedding ----------------
__global__ __launch_bounds__(256) void k_emb(const float* __restrict__ nf,
    const float* __restrict__ W, const float* __restrict__ b,
    unsigned short* __restrict__ node0)
{
    int idx = blockIdx.x*256 + threadIdx.x;
    if (idx >= NN*FF) return;
    int n = idx >> 6, c = idx & 63;
    float s = b[c];
    for (int k=0;k<OF;k++) s = fmaf(nf[(size_t)n*OF+k], W[k*FF+c], s);
    node0[idx] = f2bf(s);
}

// ---------------- slice reduce ----------------
__global__ __launch_bounds__(256) void k_red(float* __restrict__ P,
    float* __restrict__ dst, int lo, int hi)
{
    for (int c = lo + threadIdx.x; c < hi; c += 256) {
        float s = 0.f;
        #pragma unroll 8
        for (int sl = 0; sl < NSLICE; ++sl) s += P[sl*PSTRIDE + c];
        dst[c] = s;
        #pragma unroll 8
        for (int sl = 0; sl < NSLICE; ++sl) P[sl*PSTRIDE + c] = 0.f;
    }
}

// ---------------- async stage secs 0/1: 24 x glds16 per tile ----------------
// LDS layout Z0[96][128 elems]; within each 128B section, chunk c' holds logical
// chunk c'^(row&7) (source pre-swizzle so ds_read side can XOR-swizzle).
__device__ __forceinline__ void issue_glds01(char* bufbase,
    const unsigned short* __restrict__ node_src, const int* __restrict__ eidx,
    int n0, int w, int lane)
{
    const int gr0 = n0 * MM;
    #pragma unroll
    for (int ii=0; ii<3; ++ii){
        int i = w + ii*8;                 // 0..23
        int d = i*1024 + lane*16;         // LDS byte offset
        int r = d >> 8;                   // 256B per row
        int c = d & 255;
        int sec = c >> 7;
        int ch = (c >> 4) & 7;
        int k2 = ch ^ (r & 7);
        int nsrc = n0 + ((r*2731) >> 15); // r/12
        if (sec) nsrc = eidx[gr0 + r];
        glds16(node_src + (size_t)nsrc*FF + k2*8, bufbase + d);
    }
}

// fold previous layer's edge residual: e' = lrelu(e + (g - m)*is), bf16-rounded
__device__ __forceinline__ uint4 upd_edge8(uint4 e, uint4 g,
    const float* __restrict__ mmv, const float* __restrict__ isv, int ch)
{
    unsigned short es[8], gs[8], os[8];
    *(uint4*)es = e; *(uint4*)gs = g;
    #pragma unroll
    for (int j=0;j<8;j++){
        int c = ch*8+j;
        if (c < EE){
            float v = (b2f(gs[j]) - mmv[j]) * isv[j];
            os[j] = f2bf(lrelu(b2f(es[j]) + v));
        } else os[j] = es[j];
    }
    return *(uint4*)os;
}

// ---------------- reg-stage sec 2 (edges) with optional fused update ----------------
__device__ __forceinline__ void stage_sec2(char* bufbase,
    const unsigned short* __restrict__ ebuf, const unsigned short* __restrict__ gbuf,
    unsigned short* __restrict__ ebuf_wb, int n0, int tid, bool upd,
    const float* __restrict__ mmv, const float* __restrict__ isv)
{
    const int gr0 = n0 * MM;
    unsigned short* Z2 = (unsigned short*)(bufbase + ZR0);
    for (int task = tid; task < 768; task += TPB) {
        int r = task >> 3, ch = task & 7;   // ch == tid&7 always (768,512 mult of 8)
        uint4 v = make_uint4(0u,0u,0u,0u);
        if (ch < 6) {
            v = *(const uint4*)(ebuf + (size_t)(gr0+r)*ES + ch*8);
            if (upd) {
                uint4 g = *(const uint4*)(gbuf + (size_t)(gr0+r)*ES + ch*8);
                v = upd_edge8(v, g, mmv, isv, ch);
                *(uint4*)(ebuf_wb + (size_t)(gr0+r)*ES + ch*8) = v;
            }
        }
        *(uint4*)(Z2 + r*64 + ((ch ^ (r&7)) << 3)) = v;
    }
}

// ---------------- MFMA core: swizzled reads, 6 M-tiles x 2 col tiles per wave ----------------
__device__ __forceinline__ void mfma_core(const char* bufbase,
    const unsigned short* __restrict__ Wpk, int h, int sw, int lane, f32x4 (&acc)[MT][2])
{
    const int quad = lane >> 4, li = lane & 15;
    const unsigned short* Z0 = (const unsigned short*)bufbase;
    const unsigned short* Z2 = (const unsigned short*)(bufbase + ZR0);
    #pragma unroll
    for (int mt=0;mt<MT;mt++){
        acc[mt][0] = (f32x4){0.f,0.f,0.f,0.f};
        acc[mt][1] = (f32x4){0.f,0.f,0.f,0.f};
    }
    const int nt0 = h*8 + sw;
    #pragma unroll
    for (int ks=0; ks<KSTEPS; ++ks) {
        bf16x8 bfr0 = *(const bf16x8*)(Wpk + (((ks*16 + nt0    )*64 + lane) << 3));
        bf16x8 bfr1 = *(const bf16x8*)(Wpk + (((ks*16 + nt0 + 4)*64 + lane) << 3));
        bf16x8 afr[MT];
        #pragma unroll
        for (int mt=0;mt<MT;mt++){
            int row = mt*16 + li;
            int x8 = (row & 7) << 3;
            if (ks < 4)
                afr[mt] = *(const bf16x8*)(Z0 + row*128 + ((ks*32 + quad*8) ^ x8));
            else
                afr[mt] = *(const bf16x8*)(Z2 + row*64  + (((ks-4)*32 + quad*8) ^ x8));
        }
        #pragma unroll
        for (int mt=0;mt<MT;mt++){
            acc[mt][0] = __builtin_amdgcn_mfma_f32_16x16x32_bf16(afr[mt], bfr0, acc[mt][0], 0, 0, 0);
            acc[mt][1] = __builtin_amdgcn_mfma_f32_16x16x32_bf16(afr[mt], bfr1, acc[mt][1], 0, 0, 0);
        }
    }
}

// ---------------- stats epilogue ----------------
__device__ __forceinline__ void stats_epi(const f32x4 (&acc)[MT][2], int h, int sw, int lane,
    float* __restrict__ Ps)
{
    const int quad = lane>>4, li = lane&15;
    #pragma unroll
    for (int t=0;t<2;t++){
        float s=0.f, q=0.f;
        #pragma unroll
        for (int mt=0;mt<MT;mt++)
            #pragma unroll
            for (int r=0;r<4;r++){ float v = acc[mt][t][r]; s+=v; q = fmaf(v,v,q); }
        s += __shfl_xor(s,16); s += __shfl_xor(s,32);
        q += __shfl_xor(q,16); q += __shfl_xor(q,32);
        if (quad == 0) {
            int col = h*128 + t*64 + sw*16 + li;
            atomicAdd(&Ps[col], s);
            atomicAdd(&Ps[256+col], q);
        }
    }
}

// ---------------- GEMM + stats (+ fused previous-layer edge update), persistent ----------------
__global__ __launch_bounds__(TPB,4) void k_stats(
    const unsigned short* __restrict__ node_src, unsigned short* __restrict__ ebuf,
    const unsigned short* __restrict__ gbuf, const int* __restrict__ eidx,
    const unsigned short* __restrict__ Wpk,
    const float* __restrict__ gS, const float* __restrict__ gQ,
    float* __restrict__ Pst)
{
    __shared__ __align__(16) char smem[2*BUFB];
    const int tid = threadIdx.x, w = tid>>6, lane = tid&63;
    const int h = w>>2, sw = w&3;
    const bool upd = (gS != nullptr);
    const int ch = tid & 7;
    float mmv[8], isv[8];
    if (upd) {
        #pragma unroll
        for (int j=0;j<8;j++){
            int c = ch*8+j;
            float mm = 0.f, is = 0.f;
            if (c < EE) {
                mm = gS[c]*(1.f/(float)NM);
                float vv = gQ[c]*(1.f/(float)NM) - mm*mm;
                is = rsqrtf(vv + 1e-5f);
            }
            mmv[j] = mm; isv[j] = is;
        }
    }
    float* Ps = Pst + (size_t)(blockIdx.x & (NSLICE-1))*PSTRIDE;

    int t = blockIdx.x, cur = 0;
    issue_glds01(smem, node_src, eidx, t*NPB, w, lane);
    stage_sec2(smem, ebuf, gbuf, ebuf, t*NPB, tid, upd, mmv, isv);
    asm volatile("s_waitcnt vmcnt(0)" ::: "memory");
    __syncthreads();
    while (t < NTILE) {
        int tn = t + GRIDP;
        if (tn < NTILE) {
            issue_glds01(smem + (cur^1)*BUFB, node_src, eidx, tn*NPB, w, lane);
            stage_sec2(smem + (cur^1)*BUFB, ebuf, gbuf, ebuf, tn*NPB, tid, upd, mmv, isv);
        }
        f32x4 acc[MT][2];
        mfma_core(smem + cur*BUFB, Wpk, h, sw, lane, acc);
        stats_epi(acc, h, sw, lane, Ps);
        asm volatile("s_waitcnt vmcnt(0)" ::: "memory");
        __syncthreads();
        cur ^= 1; t = tn;
    }
}

// ---------------- apply pass, persistent ----------------
__global__ __launch_bounds__(TPB,4) void k_apply_re(
    const unsigned short* __restrict__ node_src, const unsigned short* __restrict__ ebuf,
    const int* __restrict__ eidx, const unsigned short* __restrict__ Wpk,
    const float* __restrict__ preS, const float* __restrict__ preQ,
    float* __restrict__ aggr, unsigned short* __restrict__ gbuf,
    float* __restrict__ Pst)
{
    __shared__ __align__(16) char smem[2*BUFB];
    const int tid = threadIdx.x, w = tid>>6, lane = tid&63;
    const int quad = lane>>4, li = lane&15;
    const int h = w>>2, sw = w&3;
    const int cg0 = sw*16 + li;
    float sc[2], bi[2];
    #pragma unroll
    for (int tt=0;tt<2;tt++){
        int col = h*128 + tt*64 + cg0;
        float mm = preS[col]*(1.f/(float)NM);
        float vv = preQ[col]*(1.f/(float)NM) - mm*mm;
        float is = rsqrtf(vv + 1e-5f);
        sc[tt] = is; bi[tt] = -mm*is;
    }
    const bool ce_ok = cg0 < EE;
    float* Ps = Pst + (size_t)(blockIdx.x & (NSLICE-1))*PSTRIDE;
    float pg = 0.f, pq = 0.f, sAcc = 0.f, sQq = 0.f;

    int t = blockIdx.x, cur = 0;
    issue_glds01(smem, node_src, eidx, t*NPB, w, lane);
    stage_sec2(smem, ebuf, nullptr, nullptr, t*NPB, tid, false, nullptr, nullptr);
    asm volatile("s_waitcnt vmcnt(0)" ::: "memory");
    __syncthreads();
    while (t < NTILE) {
        int tn = t + GRIDP;
        if (tn < NTILE) {
            issue_glds01(smem + (cur^1)*BUFB, node_src, eidx, tn*NPB, w, lane);
            stage_sec2(smem + (cur^1)*BUFB, ebuf, nullptr, nullptr, tn*NPB, tid, false, nullptr, nullptr);
        }
        f32x4 acc[MT][2];
        mfma_core(smem + cur*BUFB, Wpk, h, sw, lane, acc);
        __syncthreads();                    // cur buf dead -> gL may alias it
        float* gL = (float*)(smem + cur*BUFB);   // [96][68]
        const int n0 = t*NPB, gr0 = n0*MM;
        if (h == 0) {
            #pragma unroll
            for (int mt=0;mt<MT;mt++)
                #pragma unroll
                for (int r=0;r<4;r++){
                    int row = mt*16 + quad*4 + r;
                    float nf = fmaf(acc[mt][0][r], sc[0], bi[0]);
                    float nc = fmaf(acc[mt][1][r], sc[1], bi[1]);
                    gL[row*68 + cg0] = sigm(nf) * lrelu(nc);
                }
        } else {
            #pragma unroll
            for (int mt=0;mt<MT;mt++)
                #pragma unroll
                for (int r=0;r<4;r++){
                    int row = mt*16 + quad*4 + r;
                    float ef = fmaf(acc[mt][0][r], sc[0], bi[0]);
                    float ec = fmaf(acc[mt][1][r], sc[1], bi[1]);
                    float gv = sigm(ef)*lrelu(ec);
                    if (ce_ok) {
                        gbuf[(size_t)(gr0+row)*ES + cg0] = f2bf(gv);
                        pg += gv; pq = fmaf(gv,gv,pq);
                    }
                }
        }
        __syncthreads();
        {   // aggr: wave w handles node n0+w, lane = col
            float vsum = 0.f;
            #pragma unroll
            for (int jj=0;jj<MM;jj++) vsum += gL[(w*MM+jj)*68 + lane];
            aggr[(size_t)(n0+w)*64 + lane] = vsum;
            sAcc += vsum; sQq = fmaf(vsum,vsum,sQq);
        }
        asm volatile("s_waitcnt vmcnt(0)" ::: "memory");
        __syncthreads();
        cur ^= 1; t = tn;
    }
    pg += __shfl_xor(pg,16); pg += __shfl_xor(pg,32);
    pq += __shfl_xor(pq,16); pq += __shfl_xor(pq,32);
    if (h==1 && quad==0 && ce_ok){ atomicAdd(&Ps[640+cg0], pg); atomicAdd(&Ps[704+cg0], pq); }
    atomicAdd(&Ps[512+lane], sAcc);
    atomicAdd(&Ps[576+lane], sQq);
}

// ---------------- residual node update ----------------
__global__ __launch_bounds__(256) void k_upd_node(const unsigned short* __restrict__ cur,
    const float* __restrict__ aggr, const float* __restrict__ aS,
    const float* __restrict__ aQ, unsigned short* __restrict__ nxt)
{
    int idx = blockIdx.x*256 + threadIdx.x;
    if (idx >= NN*8) return;
    int n = idx >> 3, ch = idx & 7;
    int base = n*64 + ch*8;
    float4 a0 = *(const float4*)(aggr + base);
    float4 a1 = *(const float4*)(aggr + base + 4);
    uint4 cu = *(const uint4*)(cur + base);
    unsigned short cs[8]; *(uint4*)cs = cu;
    float av[8] = {a0.x,a0.y,a0.z,a0.w,a1.x,a1.y,a1.z,a1.w};
    unsigned short os[8];
    #pragma unroll
    for (int j=0;j<8;j++){
        int c = ch*8+j;
        float mm = aS[c]*(1.f/(float)NN);
        float vv = aQ[c]*(1.f/(float)NN) - mm*mm;
        float is = rsqrtf(vv + 1e-5f);
        float v = (av[j] - mm) * is;
        os[j] = f2bf(lrelu(b2f(cs[j]) + v));
    }
    *(uint4*)(nxt + base) = *(uint4*)os;
}

// ---------------- final heads, persistent ----------------
__global__ __launch_bounds__(TPB,4) void k_final_re(
    const unsigned short* __restrict__ node_src, const unsigned short* __restrict__ ebuf,
    const int* __restrict__ eidx, const unsigned short* __restrict__ Wpk,
    const float* __restrict__ fS, const float* __restrict__ fQ,
    const float* __restrict__ distb, float* __restrict__ out)
{
    __shared__ __align__(16) char smem[2*BUFB];
    const int tid = threadIdx.x, w = tid>>6, lane = tid&63;
    const int quad = lane>>4, li = lane&15;
    const int h = w>>2, sw = w&3;
    const int cg0 = sw*16 + li;
    float sc[2], bi[2];
    #pragma unroll
    for (int tt=0;tt<2;tt++){
        int col = h*128 + tt*64 + cg0;
        float mm = fS[col]*(1.f/(float)NM);
        float vv = fQ[col]*(1.f/(float)NM) - mm*mm;
        float is = rsqrtf(vv + 1e-5f);
        sc[tt] = is; bi[tt] = -mm*is;
    }
    const int liq = li >> 2;
    const bool wr = (li & 3) == 0;

    int t = blockIdx.x, cur = 0;
    issue_glds01(smem, node_src, eidx, t*NPB, w, lane);
    stage_sec2(smem, ebuf, nullptr, nullptr, t*NPB, tid, false, nullptr, nullptr);
    asm volatile("s_waitcnt vmcnt(0)" ::: "memory");
    __syncthreads();
    while (t < NTILE) {
        int tn = t + GRIDP;
        if (tn < NTILE) {
            issue_glds01(smem + (cur^1)*BUFB, node_src, eidx, tn*NPB, w, lane);
            stage_sec2(smem + (cur^1)*BUFB, ebuf, nullptr, nullptr, tn*NPB, tid, false, nullptr, nullptr);
        }
        f32x4 acc[MT][2];
        mfma_core(smem + cur*BUFB, Wpk, h, sw, lane, acc);
        __syncthreads();                    // cur buf dead -> bufD/C alias it
        float* bufD = (float*)(smem + cur*BUFB);          // [96][17]
        float* bufC = (float*)(smem + cur*BUFB + 8192);
        const int n0 = t*NPB, gr0 = n0*MM;
        float* buf = (h == 0) ? bufD : bufC;
        #pragma unroll
        for (int mt=0;mt<MT;mt++)
            #pragma unroll
            for (int r=0;r<4;r++){
                int row = mt*16 + quad*4 + r;
                float v0 = fmaf(acc[mt][0][r], sc[0], bi[0]);
                float v1 = fmaf(acc[mt][1][r], sc[1], bi[1]);
                float p;
                if (h == 0) {
                    float dv = distb[gr0 + row];
                    p = softpl(v0 + dv) + softpl(v1 + dv);
                } else {
                    p = softpl(v0) + softpl(v1);
                }
                p += __shfl_xor(p,1); p += __shfl_xor(p,2);
                if (wr) buf[row*17 + sw*4 + liq] = p;
            }
        __syncthreads();
        if (tid < 2*RPB) {
            int hh = tid >= RPB;
            int row = tid - (hh ? RPB : 0);
            const float* bsrc = hh ? bufC : bufD;
            float s = 0.f;
            #pragma unroll
            for (int tt=0;tt<16;tt++) s += bsrc[row*17+tt];
            size_t gr = gr0 + row;
            out[gr*2 + hh] = hh ? s * (1.f/128.f) * (1.f/(float)NN) : s * (1.f/128.f);
        }
        asm volatile("s_waitcnt vmcnt(0)" ::: "memory");
        __syncthreads();
        cur ^= 1; t = tn;
    }
}

// ---------------- launch ----------------
extern "C" void kernel_launch(void* const* d_in, const int* in_sizes, int n_in,
                              void* d_out, int out_size, void* d_ws, size_t ws_size,
                              hipStream_t stream)
{
    const float* node_fea = (const float*)d_in[0];
    const float* edge_in  = (const float*)d_in[1];
    const float* nbr_off  = (const float*)d_in[2];
    const float* apos     = (const float*)d_in[3];
    const float* cells    = (const float*)d_in[4];
    const int*   eidx     = (const int*)  d_in[5];
    const float* W_emb    = (const float*)d_in[6];
    const float* b_emb    = (const float*)d_in[7];
    const float* W_pn     = (const float*)d_in[8];
    const float* W_pe     = (const float*)d_in[10];
    const float* W_dist   = (const float*)d_in[12];
    const float* W_cst    = (const float*)d_in[14];
    float* out = (float*)d_out;
    char* ws = (char*)d_ws;

    size_t o = 0;
    auto alloc = [&](size_t bytes) { char* p = ws + o; o += (bytes + 255) & ~(size_t)255; return p; };
    unsigned short* node0 = (unsigned short*)alloc((size_t)NN*FF*2);
    unsigned short* node1 = (unsigned short*)alloc((size_t)NN*FF*2);
    unsigned short* ebuf  = (unsigned short*)alloc((size_t)NM*ES*2);
    unsigned short* gbuf  = (unsigned short*)alloc((size_t)NM*ES*2);
    float* aggr  = (float*)alloc((size_t)NN*FF*4);
    float* distb = (float*)alloc((size_t)NM*4);
    unsigned short* Wpk = (unsigned short*)alloc((size_t)4*49152*2);
    float* stats = (float*)alloc(4096*4);
    float* Pst   = (float*)alloc((size_t)NSLICE*PSTRIDE*4);

    hipMemsetAsync(stats, 0, 4096*sizeof(float), stream);
    hipMemsetAsync(Pst, 0, (size_t)NSLICE*PSTRIDE*sizeof(float), stream);
    pack_w<<<(4*49152+255)/256, 256, 0, stream>>>(W_pn, W_pe, W_dist, W_cst, Wpk);
    k_dist <<<(NM+255)/256,     256, 0, stream>>>(nbr_off, apos, cells, eidx, distb);
    k_cvt  <<<(NM*ES+255)/256,  256, 0, stream>>>(edge_in, ebuf);
    k_emb  <<<(NN*FF+255)/256,  256, 0, stream>>>(node_fea, W_emb, b_emb, node0);

    const unsigned short* ncur = node0;

    for (int l=0;l<3;l++){
        float* st = stats + l*768;
        float* preS = st;       float* preQ = st+256;
        float* aSs  = st+512;   float* aQq  = st+576;
        const unsigned short* Wl = Wpk + (size_t)l*49152;
        unsigned short* ndst = (l & 1) ? node0 : node1;
        const float* gSp = (l == 0) ? nullptr : (stats + (l-1)*768 + 640);
        const float* gQp = (l == 0) ? nullptr : (stats + (l-1)*768 + 704);

        k_stats  <<<GRIDP,TPB,0,stream>>>(ncur, ebuf, gbuf, eidx, Wl, gSp, gQp, Pst);
        k_red    <<<1,256,0,stream>>>(Pst, st, 0, 512);
        k_apply_re<<<GRIDP,TPB,0,stream>>>(ncur, ebuf, eidx, Wl, preS, preQ,
                                           aggr, gbuf, Pst);
        k_red    <<<1,256,0,stream>>>(Pst, st, 512, 768);
        k_upd_node<<<(NN*8+255)/256,256,0,stream>>>(ncur, aggr, aSs, aQq, ndst);
        ncur = ndst;
    }

    float* fSt = stats + 3*768;
    float* fS = fSt; float* fQ = fSt + 256;
    const unsigned short* Wf = Wpk + (size_t)3*49152;
    const float* gSp = stats + 2*768 + 640;
    const float* gQp = stats + 2*768 + 704;
    k_stats  <<<GRIDP,TPB,0,stream>>>(ncur, ebuf, gbuf, eidx, Wf, gSp, gQp, Pst);
    k_red    <<<1,256,0,stream>>>(Pst, fSt, 0, 512);
    k_final_re<<<GRIDP,TPB,0,stream>>>(ncur, ebuf, eidx, Wf, fS, fQ, distb, out);
}

// Round 6
// 1191.099 us; speedup vs baseline: 1.4644x; 1.4644x over previous
//
#include <hip/hip_runtime.h>
#include <math.h>

// ---------------- problem constants ----------------
#define NN 50000      // nodes
#define MM 12         // neighbors
#define NM 600000     // edges = NN*MM
#define OF 92         // orig node features
#define FF 64         // node feature dim
#define EE 41         // edge feature dim
#define ES 48         // padded edge stride (bf16), cols 41..47 = 0
#define ZZ 169        // 2*FF + EE
#define RPB 96        // rows (edges) per tile = 8 nodes * 12
#define NPB 8         // nodes per tile
#define NTILE 6250    // NN / NPB
#define KSTEPS 6      // 6 * 32 = 192 >= 169
#define MT 6          // M-tiles per tile (96/16)
#define NSLICE 64     // stats accumulator replication
#define PSTRIDE 1024  // floats per slice
#define TPB 512       // threads per block in GEMM passes (8 waves)
// LDS layout (elems are bf16; stride 72 elems = 144B -> rows step 4 banks, 2-way max)
#define Z1OFF 0       // neighbor cols 64..127: [96][72]
#define Z2OFF 13824   // edge cols 128..191:    [96][72]
#define Z0OFF 27648   // self cols 0..63 dedup: [8][72]
#define SMEMB 28800

typedef __bf16 bf16x8 __attribute__((ext_vector_type(8)));
typedef float  f32x4  __attribute__((ext_vector_type(4)));

__device__ __forceinline__ float lrelu(float x){ return fmaxf(x, 0.01f*x); }
__device__ __forceinline__ float sigm(float x){ return __builtin_amdgcn_rcpf(1.f+__expf(-x)); }
__device__ __forceinline__ float softpl(float x){ return fmaxf(x,0.f) + __logf(1.f+__expf(-fabsf(x))); }
__device__ __forceinline__ unsigned short f2bf(float f){
    __bf16 h = (__bf16)f;
    return __builtin_bit_cast(unsigned short, h);
}
__device__ __forceinline__ float b2f(unsigned short u){
    unsigned int b = ((unsigned int)u) << 16;
    return __builtin_bit_cast(float, b);
}

// ---------------- weight packing into B-fragment layout (bf16) ----------------
__global__ __launch_bounds__(256) void pack_w(const float* __restrict__ Wn,
    const float* __restrict__ We, const float* __restrict__ Wd,
    const float* __restrict__ Wc, unsigned short* __restrict__ dst)
{
    int idx = blockIdx.x*256 + threadIdx.x;
    if (idx >= 4*49152) return;
    int j    = idx & 7;
    int lane = (idx >> 3) & 63;
    int ntks = (idx >> 9) % 96;         // ks*16 + nt
    int L    = idx / 49152;
    int nt = ntks & 15, ks = ntks >> 4;
    int k   = ks*32 + (lane>>4)*8 + j;
    int col = nt*16 + (lane&15);
    float v = 0.f;
    if (k < ZZ) {
        if (L < 3) {
            if (col < 128)                       v = Wn[((size_t)L*ZZ + k)*128 + col];
            else if (col >= 128 && col < 128+EE) v = We[((size_t)L*ZZ + k)*82 + (col-128)];
            else if (col >= 192 && col < 192+EE) v = We[((size_t)L*ZZ + k)*82 + 41 + (col-192)];
        } else {
            if (col < 128) v = Wd[(size_t)k*128 + col];
            else           v = Wc[(size_t)k*128 + (col-128)];
        }
    }
    dst[idx] = f2bf(v);
}

// ---------------- distance ----------------
__global__ __launch_bounds__(256) void k_dist(const float* __restrict__ off,
    const float* __restrict__ apos, const float* __restrict__ cells,
    const int* __restrict__ eidx, float* __restrict__ distb)
{
    int idx = blockIdx.x*256 + threadIdx.x;
    if (idx >= NM) return;
    int n = idx / MM;
    const float* o  = off + (size_t)idx*3;
    const float* cl = cells + (size_t)n*9;
    int n2 = eidx[idx];
    float o0=o[0], o1=o[1], o2=o[2];
    float dd = 1e-12f;
    #pragma unroll
    for (int j=0;j<3;j++){
        float oc = o0*cl[0*3+j] + o1*cl[1*3+j] + o2*cl[2*3+j];
        float d = apos[(size_t)n2*3+j] + oc - apos[(size_t)n*3+j];
        dd += d*d;
    }
    distb[idx] = sqrtf(dd);
}

// ---------------- edge convert: fp32 [NM][41] -> bf16 [NM][48], vectorized writes ----------------
__global__ __launch_bounds__(256) void k_cvt(const float* __restrict__ src,
    unsigned short* __restrict__ e)
{
    int idx = blockIdx.x*256 + threadIdx.x;
    if (idx >= NM*6) return;
    int gr = idx / 6;
    int ch = idx - gr*6;
    const float* s = src + (size_t)gr*EE + ch*8;
    unsigned short os[8];
    #pragma unroll
    for (int j=0;j<8;j++){
        int c = ch*8+j;
        os[j] = (c < EE) ? f2bf(s[j]) : (unsigned short)0;
    }
    *(uint4*)(e + (size_t)gr*ES + ch*8) = *(uint4*)os;
}

// ---------------- embedding ----------------
__global__ __launch_bounds__(256) void k_emb(const float* __restrict__ nf,
    const float* __restrict__ W, const float* __restrict__ b,
    unsigned short* __restrict__ node0)
{
    int idx = blockIdx.x*256 + threadIdx.x;
    if (idx >= NN*FF) return;
    int n = idx >> 6, c = idx & 63;
    float s = b[c];
    for (int k=0;k<OF;k++) s = fmaf(nf[(size_t)n*OF+k], W[k*FF+c], s);
    node0[idx] = f2bf(s);
}

// ---------------- slice reduce ----------------
__global__ __launch_bounds__(256) void k_red(float* __restrict__ P,
    float* __restrict__ dst, int lo, int hi)
{
    for (int c = lo + threadIdx.x; c < hi; c += 256) {
        float s = 0.f;
        #pragma unroll 8
        for (int sl = 0; sl < NSLICE; ++sl) s += P[sl*PSTRIDE + c];
        dst[c] = s;
        #pragma unroll 8
        for (int sl = 0; sl < NSLICE; ++sl) P[sl*PSTRIDE + c] = 0.f;
    }
}

// fold previous layer's edge residual: e' = lrelu(e + (g - m)*is), bf16-rounded
__device__ __forceinline__ uint4 upd_edge8(uint4 e, uint4 g,
    const float* __restrict__ mmv, const float* __restrict__ isv, int ch)
{
    unsigned short es[8], gs[8], os[8];
    *(uint4*)es = e; *(uint4*)gs = g;
    #pragma unroll
    for (int j=0;j<8;j++){
        int c = ch*8+j;
        if (c < EE){
            float v = (b2f(gs[j]) - mmv[j]) * isv[j];
            os[j] = f2bf(lrelu(b2f(es[j]) + v));
        } else os[j] = es[j];
    }
    return *(uint4*)os;
}

// ---------------- z staging: self dedup [8][72], nbr [96][72], edge [96][72] ----------------
// UPD: fold previous-layer edge residual during edge staging (and write e' back).
template<bool UPD>
__device__ __forceinline__ void stage_z(char* smem,
    const unsigned short* __restrict__ node_src, unsigned short* __restrict__ ebuf,
    const unsigned short* __restrict__ gbuf, const int* __restrict__ eidx,
    int n0, int tid, const float* __restrict__ mmv, const float* __restrict__ isv)
{
    unsigned short* Z1 = (unsigned short*)(smem + Z1OFF);
    unsigned short* Z2 = (unsigned short*)(smem + Z2OFF);
    unsigned short* Z0 = (unsigned short*)(smem + Z0OFF);
    const int gr0 = n0 * MM;
    const int r0 = tid >> 3, ch = tid & 7;
    const bool two = tid < 256;
    const int r1 = r0 + 64;
    // neighbor gather rows
    int e0 = eidx[gr0 + r0];
    uint4 nb0 = *(const uint4*)(node_src + (size_t)e0*FF + ch*8);
    *(uint4*)(Z1 + r0*72 + ch*8) = nb0;
    if (two) {
        int e1 = eidx[gr0 + r1];
        uint4 nb1 = *(const uint4*)(node_src + (size_t)e1*FF + ch*8);
        *(uint4*)(Z1 + r1*72 + ch*8) = nb1;
    }
    // edge rows (+ optional fused residual update)
    {
        uint4 v = make_uint4(0u,0u,0u,0u);
        if (ch < 6) {
            v = *(const uint4*)(ebuf + (size_t)(gr0+r0)*ES + ch*8);
            if (UPD) {
                uint4 g = *(const uint4*)(gbuf + (size_t)(gr0+r0)*ES + ch*8);
                v = upd_edge8(v, g, mmv, isv, ch);
                *(uint4*)(ebuf + (size_t)(gr0+r0)*ES + ch*8) = v;
            }
        }
        *(uint4*)(Z2 + r0*72 + ch*8) = v;
        if (two) {
            uint4 v1 = make_uint4(0u,0u,0u,0u);
            if (ch < 6) {
                v1 = *(const uint4*)(ebuf + (size_t)(gr0+r1)*ES + ch*8);
                if (UPD) {
                    uint4 g1 = *(const uint4*)(gbuf + (size_t)(gr0+r1)*ES + ch*8);
                    v1 = upd_edge8(v1, g1, mmv, isv, ch);
                    *(uint4*)(ebuf + (size_t)(gr0+r1)*ES + ch*8) = v1;
                }
            }
            *(uint4*)(Z2 + r1*72 + ch*8) = v1;
        }
    }
    // self nodes: dedup, 8 nodes x 8 chunks, handled by last wave
    if (tid >= 448) {
        int nd = (tid - 448) >> 3;
        uint4 s = *(const uint4*)(node_src + (size_t)(n0+nd)*FF + ch*8);
        *(uint4*)(Z0 + nd*72 + ch*8) = s;
    }
}

// ---------------- MFMA core: self via row/12 dedup, 6 M-tiles x 2 col tiles per wave ----------------
__device__ __forceinline__ void mfma_core(const char* smem,
    const unsigned short* __restrict__ Wpk, int h, int sw, int lane, f32x4 (&acc)[MT][2])
{
    const int quad = lane >> 4, li = lane & 15;
    const unsigned short* Z1 = (const unsigned short*)(smem + Z1OFF);
    const unsigned short* Z2 = (const unsigned short*)(smem + Z2OFF);
    const unsigned short* Z0 = (const unsigned short*)(smem + Z0OFF);
    #pragma unroll
    for (int mt=0;mt<MT;mt++){
        acc[mt][0] = (f32x4){0.f,0.f,0.f,0.f};
        acc[mt][1] = (f32x4){0.f,0.f,0.f,0.f};
    }
    int rd12[MT];
    #pragma unroll
    for (int mt=0;mt<MT;mt++) rd12[mt] = ((mt*16 + li) * 2731) >> 15;   // row/12
    const int nt0 = h*8 + sw;
    #pragma unroll
    for (int ks=0; ks<KSTEPS; ++ks) {
        bf16x8 bfr0 = *(const bf16x8*)(Wpk + (((ks*16 + nt0    )*64 + lane) << 3));
        bf16x8 bfr1 = *(const bf16x8*)(Wpk + (((ks*16 + nt0 + 4)*64 + lane) << 3));
        bf16x8 afr[MT];
        #pragma unroll
        for (int mt=0;mt<MT;mt++){
            int row = mt*16 + li;
            if (ks < 2)
                afr[mt] = *(const bf16x8*)(Z0 + rd12[mt]*72 + ks*32 + quad*8);
            else if (ks < 4)
                afr[mt] = *(const bf16x8*)(Z1 + row*72 + (ks-2)*32 + quad*8);
            else
                afr[mt] = *(const bf16x8*)(Z2 + row*72 + (ks-4)*32 + quad*8);
        }
        #pragma unroll
        for (int mt=0;mt<MT;mt++){
            acc[mt][0] = __builtin_amdgcn_mfma_f32_16x16x32_bf16(afr[mt], bfr0, acc[mt][0], 0, 0, 0);
            acc[mt][1] = __builtin_amdgcn_mfma_f32_16x16x32_bf16(afr[mt], bfr1, acc[mt][1], 0, 0, 0);
        }
    }
}

// ---------------- stats epilogue ----------------
__device__ __forceinline__ void stats_epi(const f32x4 (&acc)[MT][2], int h, int sw, int lane,
    float* __restrict__ Ps)
{
    const int quad = lane>>4, li = lane&15;
    #pragma unroll
    for (int t=0;t<2;t++){
        float s=0.f, q=0.f;
        #pragma unroll
        for (int mt=0;mt<MT;mt++)
            #pragma unroll
            for (int r=0;r<4;r++){ float v = acc[mt][t][r]; s+=v; q = fmaf(v,v,q); }
        s += __shfl_xor(s,16); s += __shfl_xor(s,32);
        q += __shfl_xor(q,16); q += __shfl_xor(q,32);
        if (quad == 0) {
            int col = h*128 + t*64 + sw*16 + li;
            atomicAdd(&Ps[col], s);
            atomicAdd(&Ps[256+col], q);
        }
    }
}

// ---------------- GEMM + stats (+ fused previous-layer edge update) ----------------
template<bool UPD>
__device__ __forceinline__ void k_stats_body(
    const unsigned short* __restrict__ node_src, unsigned short* __restrict__ ebuf,
    const unsigned short* __restrict__ gbuf, const int* __restrict__ eidx,
    const unsigned short* __restrict__ Wpk,
    const float* __restrict__ gS, const float* __restrict__ gQ,
    float* __restrict__ Pst)
{
    __shared__ __align__(16) char smem[SMEMB];
    const int tid = threadIdx.x, w = tid>>6, lane = tid&63;
    const int h = w>>2, sw = w&3;
    const int ch = tid & 7;
    float mmv[8], isv[8];
    if (UPD) {
        #pragma unroll
        for (int j=0;j<8;j++){
            int c = ch*8+j;
            float mm = 0.f, is = 0.f;
            if (c < EE) {
                mm = gS[c]*(1.f/(float)NM);
                float vv = gQ[c]*(1.f/(float)NM) - mm*mm;
                is = rsqrtf(vv + 1e-5f);
            }
            mmv[j] = mm; isv[j] = is;
        }
    }
    const int n0 = blockIdx.x * NPB;
    stage_z<UPD>(smem, node_src, ebuf, gbuf, eidx, n0, tid, mmv, isv);
    __syncthreads();
    f32x4 acc[MT][2];
    mfma_core(smem, Wpk, h, sw, lane, acc);
    float* Ps = Pst + (size_t)(blockIdx.x & (NSLICE-1))*PSTRIDE;
    stats_epi(acc, h, sw, lane, Ps);
}

__global__ __launch_bounds__(TPB,3) void k_stats0(
    const unsigned short* __restrict__ node_src, unsigned short* __restrict__ ebuf,
    const int* __restrict__ eidx, const unsigned short* __restrict__ Wpk,
    float* __restrict__ Pst)
{
    k_stats_body<false>(node_src, ebuf, nullptr, eidx, Wpk, nullptr, nullptr, Pst);
}

__global__ __launch_bounds__(TPB,3) void k_stats_u(
    const unsigned short* __restrict__ node_src, unsigned short* __restrict__ ebuf,
    const unsigned short* __restrict__ gbuf, const int* __restrict__ eidx,
    const unsigned short* __restrict__ Wpk,
    const float* __restrict__ gS, const float* __restrict__ gQ,
    float* __restrict__ Pst)
{
    k_stats_body<true>(node_src, ebuf, gbuf, eidx, Wpk, gS, gQ, Pst);
}

// ---------------- apply pass (recompute GEMM) ----------------
__global__ __launch_bounds__(TPB,3) void k_apply_re(
    const unsigned short* __restrict__ node_src, unsigned short* __restrict__ ebuf,
    const int* __restrict__ eidx, const unsigned short* __restrict__ Wpk,
    const float* __restrict__ preS, const float* __restrict__ preQ,
    float* __restrict__ aggr, unsigned short* __restrict__ gbuf,
    float* __restrict__ Pst)
{
    __shared__ __align__(16) char smem[SMEMB];   // stage; gL [96][68] fp32 aliases after sync
    float* gL = (float*)smem;
    const int tid = threadIdx.x, w = tid>>6, lane = tid&63;
    const int quad = lane>>4, li = lane&15;
    const int h = w>>2, sw = w&3;
    const int n0 = blockIdx.x * NPB;
    const int gr0 = n0 * MM;
    stage_z<false>(smem, node_src, ebuf, nullptr, eidx, n0, tid, nullptr, nullptr);
    __syncthreads();
    f32x4 acc[MT][2];
    mfma_core(smem, Wpk, h, sw, lane, acc);
    __syncthreads();                 // staged Z dead -> gL may alias

    const int cg0 = sw*16 + li;
    float sc[2], bi[2];
    #pragma unroll
    for (int t=0;t<2;t++){
        int col = h*128 + t*64 + cg0;
        float mm = preS[col]*(1.f/(float)NM);
        float vv = preQ[col]*(1.f/(float)NM) - mm*mm;
        float is = rsqrtf(vv + 1e-5f);
        sc[t] = is; bi[t] = -mm*is;
    }
    const bool ce_ok = cg0 < EE;
    float* Ps = Pst + (size_t)(blockIdx.x & (NSLICE-1))*PSTRIDE;

    if (h == 0) {
        // node gate: nf = col cg0, nc = col 64+cg0
        #pragma unroll
        for (int mt=0;mt<MT;mt++)
            #pragma unroll
            for (int r=0;r<4;r++){
                int row = mt*16 + quad*4 + r;
                float nf = fmaf(acc[mt][0][r], sc[0], bi[0]);
                float nc = fmaf(acc[mt][1][r], sc[1], bi[1]);
                gL[row*68 + cg0] = sigm(nf) * lrelu(nc);
            }
    } else {
        // edge gate: ef = col 128+cg0, ec = col 192+cg0
        float pg = 0.f, pq = 0.f;
        #pragma unroll
        for (int mt=0;mt<MT;mt++)
            #pragma unroll
            for (int r=0;r<4;r++){
                int row = mt*16 + quad*4 + r;
                float ef = fmaf(acc[mt][0][r], sc[0], bi[0]);
                float ec = fmaf(acc[mt][1][r], sc[1], bi[1]);
                float gv = sigm(ef)*lrelu(ec);
                if (ce_ok) {
                    gbuf[(size_t)(gr0+row)*ES + cg0] = f2bf(gv);
                    pg += gv; pq = fmaf(gv,gv,pq);
                }
            }
        pg += __shfl_xor(pg,16); pg += __shfl_xor(pg,32);
        pq += __shfl_xor(pq,16); pq += __shfl_xor(pq,32);
        if (quad==0 && ce_ok){ atomicAdd(&Ps[640+cg0], pg); atomicAdd(&Ps[704+cg0], pq); }
    }
    __syncthreads();
    // aggr: wave w handles node n0+w (NPB == 8 waves), lane = col
    {
        float vsum = 0.f;
        #pragma unroll
        for (int jj=0;jj<MM;jj++) vsum += gL[(w*MM+jj)*68 + lane];
        aggr[(size_t)(n0+w)*64 + lane] = vsum;
        atomicAdd(&Ps[512+lane], vsum);
        atomicAdd(&Ps[576+lane], vsum*vsum);
    }
}

// ---------------- residual node update ----------------
__global__ __launch_bounds__(256) void k_upd_node(const unsigned short* __restrict__ cur,
    const float* __restrict__ aggr, const float* __restrict__ aS,
    const float* __restrict__ aQ, unsigned short* __restrict__ nxt)
{
    int idx = blockIdx.x*256 + threadIdx.x;
    if (idx >= NN*8) return;
    int n = idx >> 3, ch = idx & 7;
    int base = n*64 + ch*8;
    float4 a0 = *(const float4*)(aggr + base);
    float4 a1 = *(const float4*)(aggr + base + 4);
    uint4 cu = *(const uint4*)(cur + base);
    unsigned short cs[8]; *(uint4*)cs = cu;
    float av[8] = {a0.x,a0.y,a0.z,a0.w,a1.x,a1.y,a1.z,a1.w};
    unsigned short os[8];
    #pragma unroll
    for (int j=0;j<8;j++){
        int c = ch*8+j;
        float mm = aS[c]*(1.f/(float)NN);
        float vv = aQ[c]*(1.f/(float)NN) - mm*mm;
        float is = rsqrtf(vv + 1e-5f);
        float v = (av[j] - mm) * is;
        os[j] = f2bf(lrelu(b2f(cs[j]) + v));
    }
    *(uint4*)(nxt + base) = *(uint4*)os;
}

// ---------------- final heads (recompute GEMM) ----------------
__global__ __launch_bounds__(TPB,3) void k_final_re(
    const unsigned short* __restrict__ node_src, unsigned short* __restrict__ ebuf,
    const int* __restrict__ eidx, const unsigned short* __restrict__ Wpk,
    const float* __restrict__ fS, const float* __restrict__ fQ,
    const float* __restrict__ distb, float* __restrict__ out)
{
    __shared__ __align__(16) char smem[SMEMB];   // stage; bufD/bufC alias after sync
    float* bufD = (float*)smem;                  // [96][17]
    float* bufC = (float*)(smem + 8192);
    const int tid = threadIdx.x, w = tid>>6, lane = tid&63;
    const int quad = lane>>4, li = lane&15;
    const int h = w>>2, sw = w&3;
    const int n0 = blockIdx.x * NPB;
    const int gr0 = n0 * MM;
    stage_z<false>(smem, node_src, ebuf, nullptr, eidx, n0, tid, nullptr, nullptr);
    __syncthreads();
    f32x4 acc[MT][2];
    mfma_core(smem, Wpk, h, sw, lane, acc);
    __syncthreads();

    const int cg0 = sw*16 + li;
    float sc[2], bi[2];
    #pragma unroll
    for (int t=0;t<2;t++){
        int col = h*128 + t*64 + cg0;
        float mm = fS[col]*(1.f/(float)NM);
        float vv = fQ[col]*(1.f/(float)NM) - mm*mm;
        float is = rsqrtf(vv + 1e-5f);
        sc[t] = is; bi[t] = -mm*is;
    }
    const int liq = li >> 2;
    const bool wr = (li & 3) == 0;
    float* buf = (h == 0) ? bufD : bufC;
    #pragma unroll
    for (int mt=0;mt<MT;mt++)
        #pragma unroll
        for (int r=0;r<4;r++){
            int row = mt*16 + quad*4 + r;
            float v0 = fmaf(acc[mt][0][r], sc[0], bi[0]);
            float v1 = fmaf(acc[mt][1][r], sc[1], bi[1]);
            float p;
            if (h == 0) {
                float dv = distb[gr0 + row];
                p = softpl(v0 + dv) + softpl(v1 + dv);
            } else {
                p = softpl(v0) + softpl(v1);
            }
            p += __shfl_xor(p,1); p += __shfl_xor(p,2);
            if (wr) buf[row*17 + sw*4 + liq] = p;
        }
    __syncthreads();
    if (tid < 2*RPB) {
        int hh = tid >= RPB;
        int row = tid - (hh ? RPB : 0);
        const float* bsrc = hh ? bufC : bufD;
        float s = 0.f;
        #pragma unroll
        for (int t=0;t<16;t++) s += bsrc[row*17+t];
        size_t gr = gr0 + row;
        out[gr*2 + hh] = hh ? s * (1.f/128.f) * (1.f/(float)NN) : s * (1.f/128.f);
    }
}

// ---------------- launch ----------------
extern "C" void kernel_launch(void* const* d_in, const int* in_sizes, int n_in,
                              void* d_out, int out_size, void* d_ws, size_t ws_size,
                              hipStream_t stream)
{
    const float* node_fea = (const float*)d_in[0];
    const float* edge_in  = (const float*)d_in[1];
    const float* nbr_off  = (const float*)d_in[2];
    const float* apos     = (const float*)d_in[3];
    const float* cells    = (const float*)d_in[4];
    const int*   eidx     = (const int*)  d_in[5];
    const float* W_emb    = (const float*)d_in[6];
    const float* b_emb    = (const float*)d_in[7];
    const float* W_pn     = (const float*)d_in[8];
    const float* W_pe     = (const float*)d_in[10];
    const float* W_dist   = (const float*)d_in[12];
    const float* W_cst    = (const float*)d_in[14];
    float* out = (float*)d_out;
    char* ws = (char*)d_ws;

    size_t o = 0;
    auto alloc = [&](size_t bytes) { char* p = ws + o; o += (bytes + 255) & ~(size_t)255; return p; };
    unsigned short* node0 = (unsigned short*)alloc((size_t)NN*FF*2);
    unsigned short* node1 = (unsigned short*)alloc((size_t)NN*FF*2);
    unsigned short* ebuf  = (unsigned short*)alloc((size_t)NM*ES*2);
    unsigned short* gbuf  = (unsigned short*)alloc((size_t)NM*ES*2);
    float* aggr  = (float*)alloc((size_t)NN*FF*4);
    float* distb = (float*)alloc((size_t)NM*4);
    unsigned short* Wpk = (unsigned short*)alloc((size_t)4*49152*2);
    float* stats = (float*)alloc(4096*4);
    float* Pst   = (float*)alloc((size_t)NSLICE*PSTRIDE*4);

    hipMemsetAsync(stats, 0, 4096*sizeof(float), stream);
    hipMemsetAsync(Pst, 0, (size_t)NSLICE*PSTRIDE*sizeof(float), stream);
    pack_w<<<(4*49152+255)/256, 256, 0, stream>>>(W_pn, W_pe, W_dist, W_cst, Wpk);
    k_dist <<<(NM+255)/256,     256, 0, stream>>>(nbr_off, apos, cells, eidx, distb);
    k_cvt  <<<(NM*6+255)/256,   256, 0, stream>>>(edge_in, ebuf);
    k_emb  <<<(NN*FF+255)/256,  256, 0, stream>>>(node_fea, W_emb, b_emb, node0);

    const unsigned short* ncur = node0;

    for (int l=0;l<3;l++){
        float* st = stats + l*768;
        float* preS = st;       float* preQ = st+256;
        float* aSs  = st+512;   float* aQq  = st+576;
        const unsigned short* Wl = Wpk + (size_t)l*49152;
        unsigned short* ndst = (l & 1) ? node0 : node1;

        if (l == 0) {
            k_stats0 <<<NTILE,TPB,0,stream>>>((const unsigned short*)ncur, ebuf, eidx, Wl, Pst);
        } else {
            const float* gSp = stats + (l-1)*768 + 640;
            const float* gQp = stats + (l-1)*768 + 704;
            k_stats_u<<<NTILE,TPB,0,stream>>>((const unsigned short*)ncur, ebuf, gbuf, eidx,
                                              Wl, gSp, gQp, Pst);
        }
        k_red    <<<1,256,0,stream>>>(Pst, st, 0, 512);
        k_apply_re<<<NTILE,TPB,0,stream>>>((const unsigned short*)ncur, ebuf, eidx, Wl,
                                           preS, preQ, aggr, gbuf, Pst);
        k_red    <<<1,256,0,stream>>>(Pst, st, 512, 768);
        k_upd_node<<<(NN*8+255)/256,256,0,stream>>>(ncur, aggr, aSs, aQq, ndst);
        ncur = ndst;
    }

    float* fSt = stats + 3*768;
    float* fS = fSt; float* fQ = fSt + 256;
    const unsigned short* Wf = Wpk + (size_t)3*49152;
    const float* gSp = stats + 2*768 + 640;
    const float* gQp = stats + 2*768 + 704;
    k_stats_u<<<NTILE,TPB,0,stream>>>((const unsigned short*)ncur, ebuf, gbuf, eidx,
                                      Wf, gSp, gQp, Pst);
    k_red    <<<1,256,0,stream>>>(Pst, fSt, 0, 512);
    k_final_re<<<NTILE,TPB,0,stream>>>((const unsigned short*)ncur, ebuf, eidx, Wf,
                                       fS, fQ, distb, out);
}

// Round 7
// 1156.544 us; speedup vs baseline: 1.5081x; 1.0299x over previous
//
#include <hip/hip_runtime.h>
#include <math.h>

// ---------------- problem constants ----------------
#define NN 50000      // nodes
#define MM 12         // neighbors
#define NM 600000     // edges = NN*MM
#define OF 92         // orig node features
#define FF 64         // node feature dim
#define EE 41         // edge feature dim
#define ES 48         // padded edge stride (bf16), cols 41..47 = 0
#define ZZ 169        // 2*FF + EE
#define RPB 96        // rows (edges) per tile = 8 nodes * 12
#define NPB 8         // nodes per tile
#define NTILE 6250    // NN / NPB
#define KSTEPS 6      // 6 * 32 = 192 >= 169
#define MT 6          // M-tiles per tile (96/16)
#define NSLICE 64     // stats accumulator replication
#define PSTRIDE 1024  // floats per slice
#define TPB 512       // threads per block in GEMM passes (8 waves)
// LDS layout (elems are bf16; stride 72 elems = 144B -> rows step 4 banks, 2-way max)
#define Z1OFF 0       // neighbor cols 64..127: [96][72]
#define Z2OFF 13824   // edge cols 128..191:    [96][72]
#define Z0OFF 27648   // self cols 0..63 dedup: [8][72]
#define SMEMB 28800

typedef __bf16 bf16x8 __attribute__((ext_vector_type(8)));
typedef float  f32x4  __attribute__((ext_vector_type(4)));

__device__ __forceinline__ float lrelu(float x){ return fmaxf(x, 0.01f*x); }
__device__ __forceinline__ float sigm(float x){ return __builtin_amdgcn_rcpf(1.f+__expf(-x)); }
__device__ __forceinline__ float softpl(float x){ return fmaxf(x,0.f) + __logf(1.f+__expf(-fabsf(x))); }
__device__ __forceinline__ unsigned short f2bf(float f){
    __bf16 h = (__bf16)f;
    return __builtin_bit_cast(unsigned short, h);
}
__device__ __forceinline__ float b2f(unsigned short u){
    unsigned int b = ((unsigned int)u) << 16;
    return __builtin_bit_cast(float, b);
}

// ---------------- weight packing into B-fragment layout (bf16) ----------------
__global__ __launch_bounds__(256) void pack_w(const float* __restrict__ Wn,
    const float* __restrict__ We, const float* __restrict__ Wd,
    const float* __restrict__ Wc, unsigned short* __restrict__ dst)
{
    int idx = blockIdx.x*256 + threadIdx.x;
    if (idx >= 4*49152) return;
    int j    = idx & 7;
    int lane = (idx >> 3) & 63;
    int ntks = (idx >> 9) % 96;         // ks*16 + nt
    int L    = idx / 49152;
    int nt = ntks & 15, ks = ntks >> 4;
    int k   = ks*32 + (lane>>4)*8 + j;
    int col = nt*16 + (lane&15);
    float v = 0.f;
    if (k < ZZ) {
        if (L < 3) {
            if (col < 128)                       v = Wn[((size_t)L*ZZ + k)*128 + col];
            else if (col >= 128 && col < 128+EE) v = We[((size_t)L*ZZ + k)*82 + (col-128)];
            else if (col >= 192 && col < 192+EE) v = We[((size_t)L*ZZ + k)*82 + 41 + (col-192)];
        } else {
            if (col < 128) v = Wd[(size_t)k*128 + col];
            else           v = Wc[(size_t)k*128 + (col-128)];
        }
    }
    dst[idx] = f2bf(v);
}

// ---------------- distance ----------------
__global__ __launch_bounds__(256) void k_dist(const float* __restrict__ off,
    const float* __restrict__ apos, const float* __restrict__ cells,
    const int* __restrict__ eidx, float* __restrict__ distb)
{
    int idx = blockIdx.x*256 + threadIdx.x;
    if (idx >= NM) return;
    int n = idx / MM;
    const float* o  = off + (size_t)idx*3;
    const float* cl = cells + (size_t)n*9;
    int n2 = eidx[idx];
    float o0=o[0], o1=o[1], o2=o[2];
    float dd = 1e-12f;
    #pragma unroll
    for (int j=0;j<3;j++){
        float oc = o0*cl[0*3+j] + o1*cl[1*3+j] + o2*cl[2*3+j];
        float d = apos[(size_t)n2*3+j] + oc - apos[(size_t)n*3+j];
        dd += d*d;
    }
    distb[idx] = sqrtf(dd);
}

// ---------------- edge convert: fp32 [NM][41] -> bf16 [NM][48], vectorized writes ----------------
__global__ __launch_bounds__(256) void k_cvt(const float* __restrict__ src,
    unsigned short* __restrict__ e)
{
    int idx = blockIdx.x*256 + threadIdx.x;
    if (idx >= NM*6) return;
    int gr = idx / 6;
    int ch = idx - gr*6;
    const float* s = src + (size_t)gr*EE + ch*8;
    unsigned short os[8];
    #pragma unroll
    for (int j=0;j<8;j++){
        int c = ch*8+j;
        os[j] = (c < EE) ? f2bf(s[j]) : (unsigned short)0;
    }
    *(uint4*)(e + (size_t)gr*ES + ch*8) = *(uint4*)os;
}

// ---------------- embedding: LDS-staged W + nf rows, 32 nodes/block ----------------
__global__ __launch_bounds__(256) void k_emb(const float* __restrict__ nf,
    const float* __restrict__ W, const float* __restrict__ b,
    unsigned short* __restrict__ node0)
{
    __shared__ float Wl[OF*FF];      // 23.5 KB
    __shared__ float bl[FF];
    __shared__ float nfl[32*OF];     // 11.8 KB
    const int tid = threadIdx.x;
    const int n0 = blockIdx.x * 32;
    // stage W (5888 floats = 1472 float4, 16B-aligned)
    for (int i = tid; i < (OF*FF)/4; i += 256)
        ((float4*)Wl)[i] = ((const float4*)W)[i];
    if (tid < FF) bl[tid] = b[tid];
    // stage nf rows (flat contiguous: 32*92 = 2944 floats = 736 float4; 92*4B = 368 ≡ 0 mod 16)
    {
        const int lim4 = (min(32, NN - n0) * OF) / 4;
        const float4* src4 = (const float4*)(nf + (size_t)n0*OF);
        for (int i = tid; i < lim4; i += 256)
            ((float4*)nfl)[i] = src4[i];
    }
    __syncthreads();
    const int nl = tid >> 3;
    const int c0 = (tid & 7) * 8;
    if (n0 + nl >= NN) return;
    float acc[8];
    #pragma unroll
    for (int j=0;j<8;j++) acc[j] = bl[c0+j];
    for (int k=0;k<OF;k++){
        float x = nfl[nl*OF + k];
        const float4 w0 = *(const float4*)(Wl + k*FF + c0);
        const float4 w1 = *(const float4*)(Wl + k*FF + c0 + 4);
        acc[0] = fmaf(x, w0.x, acc[0]); acc[1] = fmaf(x, w0.y, acc[1]);
        acc[2] = fmaf(x, w0.z, acc[2]); acc[3] = fmaf(x, w0.w, acc[3]);
        acc[4] = fmaf(x, w1.x, acc[4]); acc[5] = fmaf(x, w1.y, acc[5]);
        acc[6] = fmaf(x, w1.z, acc[6]); acc[7] = fmaf(x, w1.w, acc[7]);
    }
    unsigned short os[8];
    #pragma unroll
    for (int j=0;j<8;j++) os[j] = f2bf(acc[j]);
    *(uint4*)(node0 + (size_t)(n0+nl)*FF + c0) = *(uint4*)os;
}

// ---------------- slice reduce ----------------
__global__ __launch_bounds__(256) void k_red(float* __restrict__ P,
    float* __restrict__ dst, int lo, int hi)
{
    for (int c = lo + threadIdx.x; c < hi; c += 256) {
        float s = 0.f;
        #pragma unroll 8
        for (int sl = 0; sl < NSLICE; ++sl) s += P[sl*PSTRIDE + c];
        dst[c] = s;
        #pragma unroll 8
        for (int sl = 0; sl < NSLICE; ++sl) P[sl*PSTRIDE + c] = 0.f;
    }
}

// fold previous layer's edge residual: e' = lrelu(e + (g - m)*is), bf16-rounded
__device__ __forceinline__ uint4 upd_edge8(uint4 e, uint4 g,
    const float* __restrict__ mmv, const float* __restrict__ isv, int ch)
{
    unsigned short es[8], gs[8], os[8];
    *(uint4*)es = e; *(uint4*)gs = g;
    #pragma unroll
    for (int j=0;j<8;j++){
        int c = ch*8+j;
        if (c < EE){
            float v = (b2f(gs[j]) - mmv[j]) * isv[j];
            os[j] = f2bf(lrelu(b2f(es[j]) + v));
        } else os[j] = es[j];
    }
    return *(uint4*)os;
}

// ---------------- z staging: self dedup [8][72], nbr [96][72], edge [96][72] ----------------
template<bool UPD>
__device__ __forceinline__ void stage_z(char* smem,
    const unsigned short* __restrict__ node_src, unsigned short* __restrict__ ebuf,
    const unsigned short* __restrict__ gbuf, const int* __restrict__ eidx,
    int n0, int tid, const float* __restrict__ mmv, const float* __restrict__ isv)
{
    unsigned short* Z1 = (unsigned short*)(smem + Z1OFF);
    unsigned short* Z2 = (unsigned short*)(smem + Z2OFF);
    unsigned short* Z0 = (unsigned short*)(smem + Z0OFF);
    const int gr0 = n0 * MM;
    const int r0 = tid >> 3, ch = tid & 7;
    const bool two = tid < 256;
    const int r1 = r0 + 64;
    // neighbor gather rows
    int e0 = eidx[gr0 + r0];
    uint4 nb0 = *(const uint4*)(node_src + (size_t)e0*FF + ch*8);
    *(uint4*)(Z1 + r0*72 + ch*8) = nb0;
    if (two) {
        int e1 = eidx[gr0 + r1];
        uint4 nb1 = *(const uint4*)(node_src + (size_t)e1*FF + ch*8);
        *(uint4*)(Z1 + r1*72 + ch*8) = nb1;
    }
    // edge rows (+ optional fused residual update)
    {
        uint4 v = make_uint4(0u,0u,0u,0u);
        if (ch < 6) {
            v = *(const uint4*)(ebuf + (size_t)(gr0+r0)*ES + ch*8);
            if (UPD) {
                uint4 g = *(const uint4*)(gbuf + (size_t)(gr0+r0)*ES + ch*8);
                v = upd_edge8(v, g, mmv, isv, ch);
                *(uint4*)(ebuf + (size_t)(gr0+r0)*ES + ch*8) = v;
            }
        }
        *(uint4*)(Z2 + r0*72 + ch*8) = v;
        if (two) {
            uint4 v1 = make_uint4(0u,0u,0u,0u);
            if (ch < 6) {
                v1 = *(const uint4*)(ebuf + (size_t)(gr0+r1)*ES + ch*8);
                if (UPD) {
                    uint4 g1 = *(const uint4*)(gbuf + (size_t)(gr0+r1)*ES + ch*8);
                    v1 = upd_edge8(v1, g1, mmv, isv, ch);
                    *(uint4*)(ebuf + (size_t)(gr0+r1)*ES + ch*8) = v1;
                }
            }
            *(uint4*)(Z2 + r1*72 + ch*8) = v1;
        }
    }
    // self nodes: dedup, 8 nodes x 8 chunks, handled by last wave
    if (tid >= 448) {
        int nd = (tid - 448) >> 3;
        uint4 s = *(const uint4*)(node_src + (size_t)(n0+nd)*FF + ch*8);
        *(uint4*)(Z0 + nd*72 + ch*8) = s;
    }
}

// ---------------- MFMA core: self via row/12 dedup, 6 M-tiles x 2 col tiles per wave ----------------
__device__ __forceinline__ void mfma_core(const char* smem,
    const unsigned short* __restrict__ Wpk, int h, int sw, int lane, f32x4 (&acc)[MT][2])
{
    const int quad = lane >> 4, li = lane & 15;
    const unsigned short* Z1 = (const unsigned short*)(smem + Z1OFF);
    const unsigned short* Z2 = (const unsigned short*)(smem + Z2OFF);
    const unsigned short* Z0 = (const unsigned short*)(smem + Z0OFF);
    #pragma unroll
    for (int mt=0;mt<MT;mt++){
        acc[mt][0] = (f32x4){0.f,0.f,0.f,0.f};
        acc[mt][1] = (f32x4){0.f,0.f,0.f,0.f};
    }
    int rd12[MT];
    #pragma unroll
    for (int mt=0;mt<MT;mt++) rd12[mt] = ((mt*16 + li) * 2731) >> 15;   // row/12
    const int nt0 = h*8 + sw;
    #pragma unroll
    for (int ks=0; ks<KSTEPS; ++ks) {
        bf16x8 bfr0 = *(const bf16x8*)(Wpk + (((ks*16 + nt0    )*64 + lane) << 3));
        bf16x8 bfr1 = *(const bf16x8*)(Wpk + (((ks*16 + nt0 + 4)*64 + lane) << 3));
        bf16x8 afr[MT];
        #pragma unroll
        for (int mt=0;mt<MT;mt++){
            int row = mt*16 + li;
            if (ks < 2)
                afr[mt] = *(const bf16x8*)(Z0 + rd12[mt]*72 + ks*32 + quad*8);
            else if (ks < 4)
                afr[mt] = *(const bf16x8*)(Z1 + row*72 + (ks-2)*32 + quad*8);
            else
                afr[mt] = *(const bf16x8*)(Z2 + row*72 + (ks-4)*32 + quad*8);
        }
        #pragma unroll
        for (int mt=0;mt<MT;mt++){
            acc[mt][0] = __builtin_amdgcn_mfma_f32_16x16x32_bf16(afr[mt], bfr0, acc[mt][0], 0, 0, 0);
            acc[mt][1] = __builtin_amdgcn_mfma_f32_16x16x32_bf16(afr[mt], bfr1, acc[mt][1], 0, 0, 0);
        }
    }
}

// ---------------- stats epilogue ----------------
__device__ __forceinline__ void stats_epi(const f32x4 (&acc)[MT][2], int h, int sw, int lane,
    float* __restrict__ Ps)
{
    const int quad = lane>>4, li = lane&15;
    #pragma unroll
    for (int t=0;t<2;t++){
        float s=0.f, q=0.f;
        #pragma unroll
        for (int mt=0;mt<MT;mt++)
            #pragma unroll
            for (int r=0;r<4;r++){ float v = acc[mt][t][r]; s+=v; q = fmaf(v,v,q); }
        s += __shfl_xor(s,16); s += __shfl_xor(s,32);
        q += __shfl_xor(q,16); q += __shfl_xor(q,32);
        if (quad == 0) {
            int col = h*128 + t*64 + sw*16 + li;
            atomicAdd(&Ps[col], s);
            atomicAdd(&Ps[256+col], q);
        }
    }
}

// ---------------- GEMM + stats (+ fused previous-layer edge update) ----------------
template<bool UPD>
__device__ __forceinline__ void k_stats_body(
    const unsigned short* __restrict__ node_src, unsigned short* __restrict__ ebuf,
    const unsigned short* __restrict__ gbuf, const int* __restrict__ eidx,
    const unsigned short* __restrict__ Wpk,
    const float* __restrict__ gS, const float* __restrict__ gQ,
    float* __restrict__ Pst)
{
    __shared__ __align__(16) char smem[SMEMB];
    const int tid = threadIdx.x, w = tid>>6, lane = tid&63;
    const int h = w>>2, sw = w&3;
    const int ch = tid & 7;
    float mmv[8], isv[8];
    if (UPD) {
        #pragma unroll
        for (int j=0;j<8;j++){
            int c = ch*8+j;
            float mm = 0.f, is = 0.f;
            if (c < EE) {
                mm = gS[c]*(1.f/(float)NM);
                float vv = gQ[c]*(1.f/(float)NM) - mm*mm;
                is = rsqrtf(vv + 1e-5f);
            }
            mmv[j] = mm; isv[j] = is;
        }
    }
    const int n0 = blockIdx.x * NPB;
    stage_z<UPD>(smem, node_src, ebuf, gbuf, eidx, n0, tid, mmv, isv);
    __syncthreads();
    f32x4 acc[MT][2];
    mfma_core(smem, Wpk, h, sw, lane, acc);
    float* Ps = Pst + (size_t)(blockIdx.x & (NSLICE-1))*PSTRIDE;
    stats_epi(acc, h, sw, lane, Ps);
}

__global__ __launch_bounds__(TPB,3) void k_stats0(
    const unsigned short* __restrict__ node_src, unsigned short* __restrict__ ebuf,
    const int* __restrict__ eidx, const unsigned short* __restrict__ Wpk,
    float* __restrict__ Pst)
{
    k_stats_body<false>(node_src, ebuf, nullptr, eidx, Wpk, nullptr, nullptr, Pst);
}

__global__ __launch_bounds__(TPB,3) void k_stats_u(
    const unsigned short* __restrict__ node_src, unsigned short* __restrict__ ebuf,
    const unsigned short* __restrict__ gbuf, const int* __restrict__ eidx,
    const unsigned short* __restrict__ Wpk,
    const float* __restrict__ gS, const float* __restrict__ gQ,
    float* __restrict__ Pst)
{
    k_stats_body<true>(node_src, ebuf, gbuf, eidx, Wpk, gS, gQ, Pst);
}

// ---------------- apply pass (recompute GEMM), non-aliased gL ----------------
__global__ __launch_bounds__(TPB,3) void k_apply_re(
    const unsigned short* __restrict__ node_src, unsigned short* __restrict__ ebuf,
    const int* __restrict__ eidx, const unsigned short* __restrict__ Wpk,
    const float* __restrict__ preS, const float* __restrict__ preQ,
    float* __restrict__ aggr, unsigned short* __restrict__ gbuf,
    float* __restrict__ Pst)
{
    __shared__ __align__(16) char smem[SMEMB];
    __shared__ float gL[RPB*68];                 // separate: no alias barrier needed
    const int tid = threadIdx.x, w = tid>>6, lane = tid&63;
    const int quad = lane>>4, li = lane&15;
    const int h = w>>2, sw = w&3;
    const int n0 = blockIdx.x * NPB;
    const int gr0 = n0 * MM;
    stage_z<false>(smem, node_src, ebuf, nullptr, eidx, n0, tid, nullptr, nullptr);
    __syncthreads();
    f32x4 acc[MT][2];
    mfma_core(smem, Wpk, h, sw, lane, acc);

    const int cg0 = sw*16 + li;
    float sc[2], bi[2];
    #pragma unroll
    for (int t=0;t<2;t++){
        int col = h*128 + t*64 + cg0;
        float mm = preS[col]*(1.f/(float)NM);
        float vv = preQ[col]*(1.f/(float)NM) - mm*mm;
        float is = rsqrtf(vv + 1e-5f);
        sc[t] = is; bi[t] = -mm*is;
    }
    const bool ce_ok = cg0 < EE;
    float* Ps = Pst + (size_t)(blockIdx.x & (NSLICE-1))*PSTRIDE;

    if (h == 0) {
        // node gate: nf = col cg0, nc = col 64+cg0
        #pragma unroll
        for (int mt=0;mt<MT;mt++)
            #pragma unroll
            for (int r=0;r<4;r++){
                int row = mt*16 + quad*4 + r;
                float nf = fmaf(acc[mt][0][r], sc[0], bi[0]);
                float nc = fmaf(acc[mt][1][r], sc[1], bi[1]);
                gL[row*68 + cg0] = sigm(nf) * lrelu(nc);
            }
    } else {
        // edge gate: ef = col 128+cg0, ec = col 192+cg0
        float pg = 0.f, pq = 0.f;
        #pragma unroll
        for (int mt=0;mt<MT;mt++)
            #pragma unroll
            for (int r=0;r<4;r++){
                int row = mt*16 + quad*4 + r;
                float ef = fmaf(acc[mt][0][r], sc[0], bi[0]);
                float ec = fmaf(acc[mt][1][r], sc[1], bi[1]);
                float gv = sigm(ef)*lrelu(ec);
                if (ce_ok) {
                    gbuf[(size_t)(gr0+row)*ES + cg0] = f2bf(gv);
                    pg += gv; pq = fmaf(gv,gv,pq);
                }
            }
        pg += __shfl_xor(pg,16); pg += __shfl_xor(pg,32);
        pq += __shfl_xor(pq,16); pq += __shfl_xor(pq,32);
        if (quad==0 && ce_ok){ atomicAdd(&Ps[640+cg0], pg); atomicAdd(&Ps[704+cg0], pq); }
    }
    __syncthreads();
    // aggr: wave w handles node n0+w (NPB == 8 waves), lane = col
    {
        float vsum = 0.f;
        #pragma unroll
        for (int jj=0;jj<MM;jj++) vsum += gL[(w*MM+jj)*68 + lane];
        aggr[(size_t)(n0+w)*64 + lane] = vsum;
        atomicAdd(&Ps[512+lane], vsum);
        atomicAdd(&Ps[576+lane], vsum*vsum);
    }
}

// ---------------- residual node update ----------------
__global__ __launch_bounds__(256) void k_upd_node(const unsigned short* __restrict__ cur,
    const float* __restrict__ aggr, const float* __restrict__ aS,
    const float* __restrict__ aQ, unsigned short* __restrict__ nxt)
{
    int idx = blockIdx.x*256 + threadIdx.x;
    if (idx >= NN*8) return;
    int n = idx >> 3, ch = idx & 7;
    int base = n*64 + ch*8;
    float4 a0 = *(const float4*)(aggr + base);
    float4 a1 = *(const float4*)(aggr + base + 4);
    uint4 cu = *(const uint4*)(cur + base);
    unsigned short cs[8]; *(uint4*)cs = cu;
    float av[8] = {a0.x,a0.y,a0.z,a0.w,a1.x,a1.y,a1.z,a1.w};
    unsigned short os[8];
    #pragma unroll
    for (int j=0;j<8;j++){
        int c = ch*8+j;
        float mm = aS[c]*(1.f/(float)NN);
        float vv = aQ[c]*(1.f/(float)NN) - mm*mm;
        float is = rsqrtf(vv + 1e-5f);
        float v = (av[j] - mm) * is;
        os[j] = f2bf(lrelu(b2f(cs[j]) + v));
    }
    *(uint4*)(nxt + base) = *(uint4*)os;
}

// ---------------- final heads (recompute GEMM), non-aliased bufs ----------------
__global__ __launch_bounds__(TPB,3) void k_final_re(
    const unsigned short* __restrict__ node_src, unsigned short* __restrict__ ebuf,
    const int* __restrict__ eidx, const unsigned short* __restrict__ Wpk,
    const float* __restrict__ fS, const float* __restrict__ fQ,
    const float* __restrict__ distb, float* __restrict__ out)
{
    __shared__ __align__(16) char smem[SMEMB];
    __shared__ float bufD[RPB*17];               // separate: no alias barrier needed
    __shared__ float bufC[RPB*17];
    const int tid = threadIdx.x, w = tid>>6, lane = tid&63;
    const int quad = lane>>4, li = lane&15;
    const int h = w>>2, sw = w&3;
    const int n0 = blockIdx.x * NPB;
    const int gr0 = n0 * MM;
    stage_z<false>(smem, node_src, ebuf, nullptr, eidx, n0, tid, nullptr, nullptr);
    __syncthreads();
    f32x4 acc[MT][2];
    mfma_core(smem, Wpk, h, sw, lane, acc);

    const int cg0 = sw*16 + li;
    float sc[2], bi[2];
    #pragma unroll
    for (int t=0;t<2;t++){
        int col = h*128 + t*64 + cg0;
        float mm = fS[col]*(1.f/(float)NM);
        float vv = fQ[col]*(1.f/(float)NM) - mm*mm;
        float is = rsqrtf(vv + 1e-5f);
        sc[t] = is; bi[t] = -mm*is;
    }
    const int liq = li >> 2;
    const bool wr = (li & 3) == 0;
    float* buf = (h == 0) ? bufD : bufC;
    #pragma unroll
    for (int mt=0;mt<MT;mt++)
        #pragma unroll
        for (int r=0;r<4;r++){
            int row = mt*16 + quad*4 + r;
            float v0 = fmaf(acc[mt][0][r], sc[0], bi[0]);
            float v1 = fmaf(acc[mt][1][r], sc[1], bi[1]);
            float p;
            if (h == 0) {
                float dv = distb[gr0 + row];
                p = softpl(v0 + dv) + softpl(v1 + dv);
            } else {
                p = softpl(v0) + softpl(v1);
            }
            p += __shfl_xor(p,1); p += __shfl_xor(p,2);
            if (wr) buf[row*17 + sw*4 + liq] = p;
        }
    __syncthreads();
    if (tid < 2*RPB) {
        int hh = tid >= RPB;
        int row = tid - (hh ? RPB : 0);
        const float* bsrc = hh ? bufC : bufD;
        float s = 0.f;
        #pragma unroll
        for (int t=0;t<16;t++) s += bsrc[row*17+t];
        size_t gr = gr0 + row;
        out[gr*2 + hh] = hh ? s * (1.f/128.f) * (1.f/(float)NN) : s * (1.f/128.f);
    }
}

// ---------------- launch ----------------
extern "C" void kernel_launch(void* const* d_in, const int* in_sizes, int n_in,
                              void* d_out, int out_size, void* d_ws, size_t ws_size,
                              hipStream_t stream)
{
    const float* node_fea = (const float*)d_in[0];
    const float* edge_in  = (const float*)d_in[1];
    const float* nbr_off  = (const float*)d_in[2];
    const float* apos     = (const float*)d_in[3];
    const float* cells    = (const float*)d_in[4];
    const int*   eidx     = (const int*)  d_in[5];
    const float* W_emb    = (const float*)d_in[6];
    const float* b_emb    = (const float*)d_in[7];
    const float* W_pn     = (const float*)d_in[8];
    const float* W_pe     = (const float*)d_in[10];
    const float* W_dist   = (const float*)d_in[12];
    const float* W_cst    = (const float*)d_in[14];
    float* out = (float*)d_out;
    char* ws = (char*)d_ws;

    size_t o = 0;
    auto alloc = [&](size_t bytes) { char* p = ws + o; o += (bytes + 255) & ~(size_t)255; return p; };
    unsigned short* node0 = (unsigned short*)alloc((size_t)NN*FF*2);
    unsigned short* node1 = (unsigned short*)alloc((size_t)NN*FF*2);
    unsigned short* ebuf  = (unsigned short*)alloc((size_t)NM*ES*2);
    unsigned short* gbuf  = (unsigned short*)alloc((size_t)NM*ES*2);
    float* aggr  = (float*)alloc((size_t)NN*FF*4);
    float* distb = (float*)alloc((size_t)NM*4);
    unsigned short* Wpk = (unsigned short*)alloc((size_t)4*49152*2);
    float* stats = (float*)alloc(4096*4);
    float* Pst   = (float*)alloc((size_t)NSLICE*PSTRIDE*4);

    hipMemsetAsync(stats, 0, 4096*sizeof(float), stream);
    hipMemsetAsync(Pst, 0, (size_t)NSLICE*PSTRIDE*sizeof(float), stream);
    pack_w<<<(4*49152+255)/256, 256, 0, stream>>>(W_pn, W_pe, W_dist, W_cst, Wpk);
    k_dist <<<(NM+255)/256,     256, 0, stream>>>(nbr_off, apos, cells, eidx, distb);
    k_cvt  <<<(NM*6+255)/256,   256, 0, stream>>>(edge_in, ebuf);
    k_emb  <<<(NN+31)/32,       256, 0, stream>>>(node_fea, W_emb, b_emb, node0);

    const unsigned short* ncur = node0;

    for (int l=0;l<3;l++){
        float* st = stats + l*768;
        float* preS = st;       float* preQ = st+256;
        float* aSs  = st+512;   float* aQq  = st+576;
        const unsigned short* Wl = Wpk + (size_t)l*49152;
        unsigned short* ndst = (l & 1) ? node0 : node1;

        if (l == 0) {
            k_stats0 <<<NTILE,TPB,0,stream>>>((const unsigned short*)ncur, ebuf, eidx, Wl, Pst);
        } else {
            const float* gSp = stats + (l-1)*768 + 640;
            const float* gQp = stats + (l-1)*768 + 704;
            k_stats_u<<<NTILE,TPB,0,stream>>>((const unsigned short*)ncur, ebuf, gbuf, eidx,
                                              Wl, gSp, gQp, Pst);
        }
        k_red    <<<1,256,0,stream>>>(Pst, st, 0, 512);
        k_apply_re<<<NTILE,TPB,0,stream>>>((const unsigned short*)ncur, ebuf, eidx, Wl,
                                           preS, preQ, aggr, gbuf, Pst);
        k_red    <<<1,256,0,stream>>>(Pst, st, 512, 768);
        k_upd_node<<<(NN*8+255)/256,256,0,stream>>>(ncur, aggr, aSs, aQq, ndst);
        ncur = ndst;
    }

    float* fSt = stats + 3*768;
    float* fS = fSt; float* fQ = fSt + 256;
    const unsigned short* Wf = Wpk + (size_t)3*49152;
    const float* gSp = stats + 2*768 + 640;
    const float* gQp = stats + 2*768 + 704;
    k_stats_u<<<NTILE,TPB,0,stream>>>((const unsigned short*)ncur, ebuf, gbuf, eidx,
                                      Wf, gSp, gQp, Pst);
    k_red    <<<1,256,0,stream>>>(Pst, fSt, 0, 512);
    k_final_re<<<NTILE,TPB,0,stream>>>((const unsigned short*)ncur, ebuf, eidx, Wf,
                                       fS, fQ, distb, out);
}